// Round 6
// baseline (233.220 us; speedup 1.0000x reference)
//
#include <hip/hip_runtime.h>
#include <stdint.h>

// Problem dims
#define R_ 8
#define B_ 16
#define S_ 512
#define H_ 1024
#define E_ 32
#define P_ 4
#define M_ (B_*S_)          // 8192 rows

// ---------------- vec chain: a_{k+1} = W2 a_k, V[k] = W1 a_k, beta_k = ab.a_k ----
// aw: answer_w [2H][H] row-major. W1 = rows [0,H), W2 = rows [H,2H).
// V: [14][H]  (q=0..6 -> v^s_k, q=7..13 -> v^m_k); betas: [16] (0..7 s, 8..15 m)
__global__ __launch_bounds__(256) void vec_chain_kernel(
    int k, const float* __restrict__ aw, const float* __restrict__ ab,
    const float* __restrict__ sw, const float* __restrict__ mw,
    float* __restrict__ a_s, float* __restrict__ a_m,
    float* __restrict__ V, float* __restrict__ betas)
{
  int w = (int)((blockIdx.x * blockDim.x + threadIdx.x) >> 6);
  int lane = threadIdx.x & 63;
  const float* as_k = (k == 0) ? (sw + 2*H_) : (a_s + (size_t)k*H_);
  const float* am_k = (k == 0) ? (mw + 2*H_) : (a_m + (size_t)k*H_);
  if (w < H_){
    const float* w1 = aw + (size_t)w * H_;
    const float* w2 = aw + (size_t)(H_ + w) * H_;
    float vs = 0.f, vm = 0.f, ns = 0.f, nm = 0.f;
    #pragma unroll
    for (int i = 0; i < 4; i++){
      int c = i*256 + lane*4;
      float4 r1 = *(const float4*)(w1 + c);
      float4 r2 = *(const float4*)(w2 + c);
      float4 xs = *(const float4*)(as_k + c);
      float4 xm = *(const float4*)(am_k + c);
      vs += r1.x*xs.x + r1.y*xs.y + r1.z*xs.z + r1.w*xs.w;
      vm += r1.x*xm.x + r1.y*xm.y + r1.z*xm.z + r1.w*xm.w;
      ns += r2.x*xs.x + r2.y*xs.y + r2.z*xs.z + r2.w*xs.w;
      nm += r2.x*xm.x + r2.y*xm.y + r2.z*xm.z + r2.w*xm.w;
    }
    #pragma unroll
    for (int m = 32; m >= 1; m >>= 1){
      vs += __shfl_xor(vs, m, 64); vm += __shfl_xor(vm, m, 64);
      ns += __shfl_xor(ns, m, 64); nm += __shfl_xor(nm, m, 64);
    }
    if (lane == 0){
      V[(size_t)k*H_ + w]       = vs;
      V[(size_t)(7 + k)*H_ + w] = vm;
      a_s[(size_t)(k+1)*H_ + w] = ns;
      a_m[(size_t)(k+1)*H_ + w] = nm;
    }
  } else if (w == H_ || w == H_ + 1){
    const float* av = (w == H_) ? as_k : am_k;
    float d = 0.f;
    #pragma unroll
    for (int i = 0; i < 4; i++){
      int c = i*256 + lane*4;
      float4 r1 = *(const float4*)(ab + c);
      float4 xs = *(const float4*)(av + c);
      d += r1.x*xs.x + r1.y*xs.y + r1.z*xs.z + r1.w*xs.w;
    }
    #pragma unroll
    for (int m = 32; m >= 1; m >>= 1) d += __shfl_xor(d, m, 64);
    if (lane == 0) betas[(w == H_ ? 0 : 8) + k] = d;
  }
}

// ---------------- persistent fused dots (grid-stride, 1440 blocks) ----
// blocks [0,1024):    sr rows (65536), sw/mw low-halves in regs
// blocks [1024,1280): tok rows (8192), tok_s + G[14] streaming
// blocks [1280,1408): ent rows (8192), mw high-half in regs
// blocks [1408,1440): init: zero PS; block 1439 wave 0: masksum + out[0]=0
__global__ __launch_bounds__(256) void dots_all_kernel(
    const float* __restrict__ sr, const float* __restrict__ tok,
    const float* __restrict__ ent, const float* __restrict__ sw,
    const float* __restrict__ mw, const float* __restrict__ V,
    const float* __restrict__ tmask,
    float* __restrict__ sr_s, float* __restrict__ sr_m,
    float* __restrict__ tok_s, float* __restrict__ ent_m,
    float* __restrict__ G, float* __restrict__ PS,
    float* __restrict__ msum, float* __restrict__ out)
{
  const int blk  = blockIdx.x;
  const int lane = threadIdx.x & 63;
  const int lw   = threadIdx.x >> 6;      // local wave 0..3

  if (blk < 1024){
    // ---- sr section: 4096 waves over 65536 rows (16 rows/wave) ----
    float4 ws[4], wm[4];
    #pragma unroll
    for (int i = 0; i < 4; i++){
      ws[i] = *(const float4*)(sw + i*256 + lane*4);
      wm[i] = *(const float4*)(mw + i*256 + lane*4);
    }
    for (int w = blk*4 + lw; w < R_*B_*S_; w += 4096){
      const float* rp = sr + (size_t)w * H_;
      float a0 = 0.f, a1 = 0.f;
      #pragma unroll
      for (int i = 0; i < 4; i++){
        float4 v = *(const float4*)(rp + i*256 + lane*4);
        a0 += v.x*ws[i].x + v.y*ws[i].y + v.z*ws[i].z + v.w*ws[i].w;
        a1 += v.x*wm[i].x + v.y*wm[i].y + v.z*wm[i].z + v.w*wm[i].w;
      }
      #pragma unroll
      for (int m = 32; m >= 1; m >>= 1){ a0 += __shfl_xor(a0, m, 64); a1 += __shfl_xor(a1, m, 64); }
      if (lane == 0){ sr_s[w] = a0; sr_m[w] = a1; }
    }
  } else if (blk < 1280){
    // ---- tok section: 1024 waves over 8192 rows (8 rows/wave), 15 dots ----
    for (int rr = (blk-1024)*4 + lw; rr < B_*S_; rr += 1024){
      const float* rp = tok + (size_t)rr * H_;
      float acc[15] = {};
      #pragma unroll
      for (int i = 0; i < 4; i++){
        int c = i*256 + lane*4;
        float4 v  = *(const float4*)(rp + c);
        float4 w0 = *(const float4*)(sw + H_ + c);
        acc[0] += v.x*w0.x + v.y*w0.y + v.z*w0.z + v.w*w0.w;
        #pragma unroll
        for (int q = 0; q < 14; q++){
          float4 vv = *(const float4*)(V + (size_t)q*H_ + c);
          acc[q+1] += v.x*vv.x + v.y*vv.y + v.z*vv.z + v.w*vv.w;
        }
      }
      #pragma unroll
      for (int q = 0; q < 15; q++)
        #pragma unroll
        for (int m = 32; m >= 1; m >>= 1) acc[q] += __shfl_xor(acc[q], m, 64);
      if (lane == 0){
        tok_s[rr] = acc[0];
        #pragma unroll
        for (int q = 0; q < 14; q++) G[(size_t)q*M_ + rr] = acc[q+1];
      }
    }
  } else if (blk < 1408){
    // ---- ent section: 512 waves over 8192 rows (16 rows/wave) ----
    float4 wmh[4];
    #pragma unroll
    for (int i = 0; i < 4; i++) wmh[i] = *(const float4*)(mw + H_ + i*256 + lane*4);
    for (int rr = (blk-1280)*4 + lw; rr < B_*S_; rr += 512){
      const float* rp = ent + (size_t)rr * H_;
      float a0 = 0.f;
      #pragma unroll
      for (int i = 0; i < 4; i++){
        float4 v = *(const float4*)(rp + i*256 + lane*4);
        a0 += v.x*wmh[i].x + v.y*wmh[i].y + v.z*wmh[i].z + v.w*wmh[i].w;
      }
      #pragma unroll
      for (int m = 32; m >= 1; m >>= 1) a0 += __shfl_xor(a0, m, 64);
      if (lane == 0) ent_m[rr] = a0;
    }
  } else {
    // ---- init section: zero PS [8][2][M] = 32768 float4s over 32 blocks ----
    int ib = blk - 1408;
    float4* p4 = (float4*)PS;
    #pragma unroll
    for (int j = 0; j < 4; j++)
      p4[(size_t)j*8192 + ib*256 + threadIdx.x] = make_float4(0.f,0.f,0.f,0.f);
    if (ib == 31 && lw == 0){
      float s = 0.f;
      for (int i = lane; i < B_*S_; i += 64) s += tmask[i];
      #pragma unroll
      for (int m = 32; m >= 1; m >>= 1) s += __shfl_xor(s, m, 64);
      if (lane == 0){ msum[0] = s; out[0] = 0.f; }
    }
  }
}

// ---------------- per-role kernel with logit handoff ---------
// grid 16 blocks (one per batch row b) x 512 threads (one per s).
__global__ __launch_bounds__(512) void role_kernel(
    int r,
    const float* __restrict__ sr_s, const float* __restrict__ sr_m,
    const float* __restrict__ tok_s, const float* __restrict__ ent_m,
    const float* __restrict__ G, const float* __restrict__ betas,
    const float* __restrict__ sb, const float* __restrict__ mb,
    const int* __restrict__ c2t, const int* __restrict__ e2t,
    const int* __restrict__ spans, const int* __restrict__ labels,
    const float* __restrict__ msum, float* __restrict__ out,
    float* __restrict__ xlog, float* __restrict__ PS)
{
  __shared__ float pta[S_];
  __shared__ float merged[S_];
  __shared__ float es[E_];
  __shared__ float red[8];
  __shared__ int   spn[E_*P_*2];
  const int b = blockIdx.x;
  const int t = threadIdx.x;
  const int bs = b*S_ + t;
  const int wid = t >> 6, lane = t & 63;

  pta[t] = 0.f;
  if (t < E_) es[t] = 0.f;
  if (t < E_*P_*2) spn[t] = spans[b*(E_*P_*2) + t];
  const int c_own = c2t[bs];
  const int e_own = e2t[bs];

  // ---- logits for all batch rows at position t ----
  float sl[B_], ml[B_];
  if (r == 0){
    const float sb0 = sb[0], mb0 = mb[0];
    #pragma unroll
    for (int bb = 0; bb < B_; bb++){
      int q = bb*S_ + t;
      sl[bb] = sr_s[q] + tok_s[q] + sb0;
      ml[bb] = sr_m[q] + ent_m[q] + mb0;
    }
  } else {
    const float* xc = xlog + (size_t)(r & 1) * (2*M_);
    #pragma unroll
    for (int bb = 0; bb < B_; bb++){
      sl[bb] = xc[bb*S_ + t];
      ml[bb] = xc[M_ + bb*S_ + t];
    }
  }
  float smax = -1e30f, mmax = -1e30f;
  #pragma unroll
  for (int bb = 0; bb < B_; bb++){ smax = fmaxf(smax, sl[bb]); mmax = fmaxf(mmax, ml[bb]); }
  float ssum = 0.f, msv = 0.f;
  #pragma unroll
  for (int bb = 0; bb < B_; bb++){ ssum += __expf(sl[bb]-smax); msv += __expf(ml[bb]-mmax); }
  float spv = __expf(sl[b]-smax) / ssum;
  float mpv = __expf(ml[b]-mmax) / msv;

  // ---- scatter own row (LDS atomics) ----
  __syncthreads();
  if (c_own >= 0) atomicAdd(&pta[c_own], spv);
  if (e_own >= 0) atomicAdd(&es[e_own], mpv);
  __syncthreads();

  // ---- span coverage + max-merge ----
  float pei = 0.f;
  #pragma unroll
  for (int e = 0; e < E_; e++){
    float sc = es[e];
    #pragma unroll
    for (int p = 0; p < P_; p++){
      int st = spn[e*8 + p*2], en = spn[e*8 + p*2 + 1];
      if (t >= st && t < en) pei += sc;
    }
  }
  float mg = fmaxf(pta[t], pei);
  merged[t] = mg;
  out[1 + (size_t)r*M_ + bs] = mg;
  __syncthreads();

  float ah_r = (c_own >= 0) ? merged[c_own] : 0.f;

  // ---- CE loss for this row ----
  float mx = mg;
  #pragma unroll
  for (int k = 32; k >= 1; k >>= 1) mx = fmaxf(mx, __shfl_xor(mx, k, 64));
  if (lane == 0) red[wid] = mx;
  __syncthreads();
  float gmx = red[0];
  #pragma unroll
  for (int i = 1; i < 8; i++) gmx = fmaxf(gmx, red[i]);
  float se = __expf(mg - gmx);
  #pragma unroll
  for (int k = 32; k >= 1; k >>= 1) se += __shfl_xor(se, k, 64);
  __syncthreads();
  if (lane == 0) red[wid] = se;
  __syncthreads();
  if (t == 0){
    float tot = 0.f;
    #pragma unroll
    for (int i = 0; i < 8; i++) tot += red[i];
    float lse = gmx + __logf(tot);
    int lbl = labels[r*B_ + b];
    float nll = lse - merged[lbl];
    atomicAdd(out, nll * msum[0] * (1.0f/16.0f));
  }

  // ---- prefix-sum update + next-role logit handoff ----
  if (r < 7){
    float ps_next = 0.f, pm_next = 0.f;
    for (int q = r + 1; q <= 7; q++){
      float gs = G[(size_t)(q-1-r)*M_ + bs];
      float gm = G[(size_t)(7 + q-1-r)*M_ + bs];
      float ns = PS[((size_t)q*2 + 0)*M_ + bs] + ah_r * gs;
      float nm = PS[((size_t)q*2 + 1)*M_ + bs] + ah_r * gm;
      PS[((size_t)q*2 + 0)*M_ + bs] = ns;
      PS[((size_t)q*2 + 1)*M_ + bs] = nm;
      if (q == r + 1){ ps_next = ns; pm_next = nm; }
    }
    float bsum_s = 0.f, bsum_m = 0.f;
    for (int k = 0; k <= r; k++){ bsum_s += betas[k]; bsum_m += betas[8 + k]; }
    float xn = sr_s[(size_t)((r+1)*B_ + b)*S_ + t] + tok_s[bs] + ps_next + sb[0] + bsum_s;
    float yn = sr_m[(size_t)((r+1)*B_ + b)*S_ + t] + ent_m[bs] + pm_next + mb[0] + bsum_m;
    float* xn_buf = xlog + (size_t)((r+1) & 1) * (2*M_);
    xn_buf[bs] = xn;
    xn_buf[M_ + bs] = yn;
  }
}

extern "C" void kernel_launch(void* const* d_in, const int* in_sizes, int n_in,
                              void* d_out, int out_size, void* d_ws, size_t ws_size,
                              hipStream_t stream){
  (void)in_sizes; (void)n_in; (void)out_size; (void)ws_size;
  const int*   labels = (const int*)  d_in[0];
  const float* sr     = (const float*)d_in[1];
  const float* tok    = (const float*)d_in[2];
  const float* ent    = (const float*)d_in[3];
  const float* tmask  = (const float*)d_in[4];
  // d_in[5] entity_mask unused by reference
  const int*   spans  = (const int*)  d_in[6];
  const int*   c2t    = (const int*)  d_in[7];
  const int*   e2t    = (const int*)  d_in[8];
  const float* sw     = (const float*)d_in[9];
  const float* sb     = (const float*)d_in[10];
  const float* mw     = (const float*)d_in[11];
  const float* mb     = (const float*)d_in[12];
  const float* aw     = (const float*)d_in[13];
  const float* ab     = (const float*)d_in[14];
  float* out = (float*)d_out;
  char*  ws  = (char*)d_ws;

  size_t o = 0;
  auto take = [&](size_t bytes){ size_t c = o; o += (bytes + 255) & ~(size_t)255; return c; };
  float* sr_s  = (float*)(ws + take((size_t)R_*B_*S_*4));
  float* sr_m  = (float*)(ws + take((size_t)R_*B_*S_*4));
  float* tok_s = (float*)(ws + take((size_t)B_*S_*4));
  float* ent_m = (float*)(ws + take((size_t)B_*S_*4));
  float* a_s   = (float*)(ws + take((size_t)8*H_*4));
  float* a_m   = (float*)(ws + take((size_t)8*H_*4));
  float* V     = (float*)(ws + take((size_t)14*H_*4));
  float* betas = (float*)(ws + take(64));
  float* G     = (float*)(ws + take((size_t)14*M_*4));
  float* PS    = (float*)(ws + take((size_t)8*2*M_*4));   // prefix sums, zeroed in dots_all
  float* xlog  = (float*)(ws + take((size_t)2*2*M_*4));   // ping-pong logit handoff
  float* msum  = (float*)(ws + take(256));

  for (int k = 0; k < 7; k++)
    vec_chain_kernel<<<257, 256, 0, stream>>>(k, aw, ab, sw, mw, a_s, a_m, V, betas);
  dots_all_kernel<<<1440, 256, 0, stream>>>(sr, tok, ent, sw, mw, V, tmask,
                                            sr_s, sr_m, tok_s, ent_m, G, PS, msum, out);
  for (int r = 0; r < R_; r++){
    role_kernel<<<16, 512, 0, stream>>>(r, sr_s, sr_m, tok_s, ent_m, G, betas,
                                        sb, mb, c2t, e2t, spans, labels, msum, out,
                                        xlog, PS);
  }
}

// Round 7
// 186.959 us; speedup vs baseline: 1.2474x; 1.2474x over previous
//
#include <hip/hip_runtime.h>
#include <stdint.h>

// Problem dims
#define R_ 8
#define B_ 16
#define S_ 512
#define H_ 1024
#define E_ 32
#define P_ 4
#define M_ (B_*S_)          // 8192 rows
#define NWAVE_ 4096         // dots grid: 1024 blocks x 256 thr

__device__ __forceinline__ float dot4(float4 a, float4 b){
  return a.x*b.x + a.y*b.y + a.z*b.z + a.w*b.w;
}

// ---------------- vec chain: a_{k+1} = W2 a_k, V[k] = W1 a_k, beta_k = ab.a_k ----
__global__ __launch_bounds__(256) void vec_chain_kernel(
    int k, const float* __restrict__ aw, const float* __restrict__ ab,
    const float* __restrict__ sw, const float* __restrict__ mw,
    float* __restrict__ a_s, float* __restrict__ a_m,
    float* __restrict__ V, float* __restrict__ betas)
{
  int w = (int)((blockIdx.x * blockDim.x + threadIdx.x) >> 6);
  int lane = threadIdx.x & 63;
  const float* as_k = (k == 0) ? (sw + 2*H_) : (a_s + (size_t)k*H_);
  const float* am_k = (k == 0) ? (mw + 2*H_) : (a_m + (size_t)k*H_);
  if (w < H_){
    const float* w1 = aw + (size_t)w * H_;
    const float* w2 = aw + (size_t)(H_ + w) * H_;
    float vs = 0.f, vm = 0.f, ns = 0.f, nm = 0.f;
    #pragma unroll
    for (int i = 0; i < 4; i++){
      int c = i*256 + lane*4;
      float4 r1 = *(const float4*)(w1 + c);
      float4 r2 = *(const float4*)(w2 + c);
      float4 xs = *(const float4*)(as_k + c);
      float4 xm = *(const float4*)(am_k + c);
      vs += dot4(r1, xs); vm += dot4(r1, xm);
      ns += dot4(r2, xs); nm += dot4(r2, xm);
    }
    #pragma unroll
    for (int m = 32; m >= 1; m >>= 1){
      vs += __shfl_xor(vs, m, 64); vm += __shfl_xor(vm, m, 64);
      ns += __shfl_xor(ns, m, 64); nm += __shfl_xor(nm, m, 64);
    }
    if (lane == 0){
      V[(size_t)k*H_ + w]       = vs;
      V[(size_t)(7 + k)*H_ + w] = vm;
      a_s[(size_t)(k+1)*H_ + w] = ns;
      a_m[(size_t)(k+1)*H_ + w] = nm;
    }
  } else if (w == H_ || w == H_ + 1){
    const float* av = (w == H_) ? as_k : am_k;
    float d = 0.f;
    #pragma unroll
    for (int i = 0; i < 4; i++){
      int c = i*256 + lane*4;
      d += dot4(*(const float4*)(ab + c), *(const float4*)(av + c));
    }
    #pragma unroll
    for (int m = 32; m >= 1; m >>= 1) d += __shfl_xor(d, m, 64);
    if (lane == 0) betas[(w == H_ ? 0 : 8) + k] = d;
  }
}

// ---------------- dots: software-pipelined, reg double-buffered ----
// 1024 blocks x 256 thr = 4096 waves, fully resident (4 blocks/CU).
// SR:  pairs p = gw + it*4096, it<8  -> rows 2p,2p+1 (8KB contiguous/step)
// TOK: half h = gw&1 const/wave; rows r0 + it*2048, it<4
// ENT: rows gw, gw+4096
// INIT: PS zero (per-thread) + masksum/out by wave 0
__global__ __launch_bounds__(256, 4) void dots_all_kernel(
    const float* __restrict__ sr, const float* __restrict__ tok,
    const float* __restrict__ ent, const float* __restrict__ sw,
    const float* __restrict__ mw, const float* __restrict__ V,
    const float* __restrict__ tmask,
    float* __restrict__ sr_s, float* __restrict__ sr_m,
    float* __restrict__ tok_s, float* __restrict__ ent_m,
    float* __restrict__ G, float* __restrict__ PS,
    float* __restrict__ msum, float* __restrict__ out)
{
  const int gtid = blockIdx.x * 256 + threadIdx.x;
  const int gw   = gtid >> 6;
  const int lane = threadIdx.x & 63;
  const int co   = lane * 4;

  // ---- INIT (first: independent, overlaps with everything) ----
  if (gtid < 32768) ((float4*)PS)[gtid] = make_float4(0.f,0.f,0.f,0.f);
  if (gw == 0){
    float s = 0.f;
    #pragma unroll
    for (int i = 0; i < 32; i++){
      float4 v = ((const float4*)tmask)[i*64 + lane];
      s += v.x + v.y + v.z + v.w;
    }
    #pragma unroll
    for (int m = 32; m >= 1; m >>= 1) s += __shfl_xor(s, m, 64);
    if (lane == 0){ msum[0] = s; out[0] = 0.f; }
  }

  // ---- SR phase ----
  {
    float4 ws[4], wm[4];
    #pragma unroll
    for (int i = 0; i < 4; i++){
      ws[i] = *(const float4*)(sw + i*256 + co);
      wm[i] = *(const float4*)(mw + i*256 + co);
    }
    float4 bufA[8], bufB[8];
    auto LDP = [&](float4* buf, int p){
      const float* r0 = sr + (size_t)p * (2*H_);
      #pragma unroll
      for (int i = 0; i < 4; i++){
        buf[i]   = *(const float4*)(r0 + i*256 + co);
        buf[4+i] = *(const float4*)(r0 + H_ + i*256 + co);
      }
    };
    auto CMP = [&](const float4* buf, int p){
      float a0=0.f,a1=0.f,b0=0.f,b1=0.f;
      #pragma unroll
      for (int i = 0; i < 4; i++){
        a0 += dot4(buf[i],   ws[i]);  a1 += dot4(buf[i],   wm[i]);
        b0 += dot4(buf[4+i], ws[i]);  b1 += dot4(buf[4+i], wm[i]);
      }
      #pragma unroll
      for (int m = 32; m >= 1; m >>= 1){
        a0 += __shfl_xor(a0,m,64); a1 += __shfl_xor(a1,m,64);
        b0 += __shfl_xor(b0,m,64); b1 += __shfl_xor(b1,m,64);
      }
      if (lane == 0){
        sr_s[2*p]   = a0; sr_m[2*p]   = a1;
        sr_s[2*p+1] = b0; sr_m[2*p+1] = b1;
      }
    };
    LDP(bufA, gw);
    #pragma unroll
    for (int it = 0; it < 8; it += 2){
      LDP(bufB, gw + (it+1)*NWAVE_);
      CMP(bufA, gw + it*NWAVE_);
      if (it + 2 < 8) LDP(bufA, gw + (it+2)*NWAVE_);
      CMP(bufB, gw + (it+1)*NWAVE_);
    }
  }

  // ---- TOK phase (half-split by wave parity; h constant per wave) ----
  {
    const int h  = gw & 1;
    const int r0 = gw >> 1;        // rows r0 + it*2048, it<4
    float4 vA[4], vB[4];
    auto LDV = [&](float4* v, int rr){
      const float* rp = tok + (size_t)rr * H_;
      #pragma unroll
      for (int i = 0; i < 4; i++) v[i] = *(const float4*)(rp + i*256 + co);
    };
    if (h == 0){
      auto CMP0 = [&](const float4* v, int rr){
        float acc[8] = {};
        #pragma unroll
        for (int i = 0; i < 4; i++){
          int c = i*256 + co;
          acc[0] += dot4(v[i], *(const float4*)(sw + H_ + c));
          #pragma unroll
          for (int q = 0; q < 7; q++)
            acc[q+1] += dot4(v[i], *(const float4*)(V + (size_t)q*H_ + c));
        }
        #pragma unroll
        for (int m = 32; m >= 1; m >>= 1)
          #pragma unroll
          for (int q = 0; q < 8; q++) acc[q] += __shfl_xor(acc[q],m,64);
        if (lane == 0){
          tok_s[rr] = acc[0];
          #pragma unroll
          for (int q = 0; q < 7; q++) G[(size_t)q*M_ + rr] = acc[q+1];
        }
      };
      LDV(vA, r0);
      LDV(vB, r0 + 2048); CMP0(vA, r0);
      LDV(vA, r0 + 4096); CMP0(vB, r0 + 2048);
      LDV(vB, r0 + 6144); CMP0(vA, r0 + 4096);
      CMP0(vB, r0 + 6144);
    } else {
      auto CMP1 = [&](const float4* v, int rr){
        float acc[7] = {};
        #pragma unroll
        for (int i = 0; i < 4; i++){
          int c = i*256 + co;
          #pragma unroll
          for (int q = 0; q < 7; q++)
            acc[q] += dot4(v[i], *(const float4*)(V + (size_t)(7+q)*H_ + c));
        }
        #pragma unroll
        for (int m = 32; m >= 1; m >>= 1)
          #pragma unroll
          for (int q = 0; q < 7; q++) acc[q] += __shfl_xor(acc[q],m,64);
        if (lane == 0){
          #pragma unroll
          for (int q = 0; q < 7; q++) G[(size_t)(7+q)*M_ + rr] = acc[q];
        }
      };
      LDV(vA, r0);
      LDV(vB, r0 + 2048); CMP1(vA, r0);
      LDV(vA, r0 + 4096); CMP1(vB, r0 + 2048);
      LDV(vB, r0 + 6144); CMP1(vA, r0 + 4096);
      CMP1(vB, r0 + 6144);
    }
  }

  // ---- ENT phase ----
  {
    float4 wmh[4];
    #pragma unroll
    for (int i = 0; i < 4; i++) wmh[i] = *(const float4*)(mw + H_ + i*256 + co);
    float4 eA[4], eB[4];
    const float* rpA = ent + (size_t)gw * H_;
    const float* rpB = ent + (size_t)(gw + 4096) * H_;
    #pragma unroll
    for (int i = 0; i < 4; i++) eA[i] = *(const float4*)(rpA + i*256 + co);
    #pragma unroll
    for (int i = 0; i < 4; i++) eB[i] = *(const float4*)(rpB + i*256 + co);
    float a0 = 0.f, b0 = 0.f;
    #pragma unroll
    for (int i = 0; i < 4; i++){ a0 += dot4(eA[i], wmh[i]); b0 += dot4(eB[i], wmh[i]); }
    #pragma unroll
    for (int m = 32; m >= 1; m >>= 1){ a0 += __shfl_xor(a0,m,64); b0 += __shfl_xor(b0,m,64); }
    if (lane == 0){ ent_m[gw] = a0; ent_m[gw + 4096] = b0; }
  }
}

// ---------------- per-role kernel with logit handoff ---------
__global__ __launch_bounds__(512) void role_kernel(
    int r,
    const float* __restrict__ sr_s, const float* __restrict__ sr_m,
    const float* __restrict__ tok_s, const float* __restrict__ ent_m,
    const float* __restrict__ G, const float* __restrict__ betas,
    const float* __restrict__ sb, const float* __restrict__ mb,
    const int* __restrict__ c2t, const int* __restrict__ e2t,
    const int* __restrict__ spans, const int* __restrict__ labels,
    const float* __restrict__ msum, float* __restrict__ out,
    float* __restrict__ xlog, float* __restrict__ PS)
{
  __shared__ float pta[S_];
  __shared__ float merged[S_];
  __shared__ float es[E_];
  __shared__ float red[8];
  __shared__ int   spn[E_*P_*2];
  const int b = blockIdx.x;
  const int t = threadIdx.x;
  const int bs = b*S_ + t;
  const int wid = t >> 6, lane = t & 63;

  pta[t] = 0.f;
  if (t < E_) es[t] = 0.f;
  if (t < E_*P_*2) spn[t] = spans[b*(E_*P_*2) + t];
  const int c_own = c2t[bs];
  const int e_own = e2t[bs];

  float sl[B_], ml[B_];
  if (r == 0){
    const float sb0 = sb[0], mb0 = mb[0];
    #pragma unroll
    for (int bb = 0; bb < B_; bb++){
      int q = bb*S_ + t;
      sl[bb] = sr_s[q] + tok_s[q] + sb0;
      ml[bb] = sr_m[q] + ent_m[q] + mb0;
    }
  } else {
    const float* xc = xlog + (size_t)(r & 1) * (2*M_);
    #pragma unroll
    for (int bb = 0; bb < B_; bb++){
      sl[bb] = xc[bb*S_ + t];
      ml[bb] = xc[M_ + bb*S_ + t];
    }
  }
  float smax = -1e30f, mmax = -1e30f;
  #pragma unroll
  for (int bb = 0; bb < B_; bb++){ smax = fmaxf(smax, sl[bb]); mmax = fmaxf(mmax, ml[bb]); }
  float ssum = 0.f, msv = 0.f;
  #pragma unroll
  for (int bb = 0; bb < B_; bb++){ ssum += __expf(sl[bb]-smax); msv += __expf(ml[bb]-mmax); }
  float spv = __expf(sl[b]-smax) / ssum;
  float mpv = __expf(ml[b]-mmax) / msv;

  __syncthreads();
  if (c_own >= 0) atomicAdd(&pta[c_own], spv);
  if (e_own >= 0) atomicAdd(&es[e_own], mpv);
  __syncthreads();

  float pei = 0.f;
  #pragma unroll
  for (int e = 0; e < E_; e++){
    float sc = es[e];
    #pragma unroll
    for (int p = 0; p < P_; p++){
      int st = spn[e*8 + p*2], en = spn[e*8 + p*2 + 1];
      if (t >= st && t < en) pei += sc;
    }
  }
  float mg = fmaxf(pta[t], pei);
  merged[t] = mg;
  out[1 + (size_t)r*M_ + bs] = mg;
  __syncthreads();

  float ah_r = (c_own >= 0) ? merged[c_own] : 0.f;

  float mx = mg;
  #pragma unroll
  for (int k = 32; k >= 1; k >>= 1) mx = fmaxf(mx, __shfl_xor(mx, k, 64));
  if (lane == 0) red[wid] = mx;
  __syncthreads();
  float gmx = red[0];
  #pragma unroll
  for (int i = 1; i < 8; i++) gmx = fmaxf(gmx, red[i]);
  float se = __expf(mg - gmx);
  #pragma unroll
  for (int k = 32; k >= 1; k >>= 1) se += __shfl_xor(se, k, 64);
  __syncthreads();
  if (lane == 0) red[wid] = se;
  __syncthreads();
  if (t == 0){
    float tot = 0.f;
    #pragma unroll
    for (int i = 0; i < 8; i++) tot += red[i];
    float lse = gmx + __logf(tot);
    int lbl = labels[r*B_ + b];
    float nll = lse - merged[lbl];
    atomicAdd(out, nll * msum[0] * (1.0f/16.0f));
  }

  if (r < 7){
    float ps_next = 0.f, pm_next = 0.f;
    for (int q = r + 1; q <= 7; q++){
      float gs = G[(size_t)(q-1-r)*M_ + bs];
      float gm = G[(size_t)(7 + q-1-r)*M_ + bs];
      float ns = PS[((size_t)q*2 + 0)*M_ + bs] + ah_r * gs;
      float nm = PS[((size_t)q*2 + 1)*M_ + bs] + ah_r * gm;
      PS[((size_t)q*2 + 0)*M_ + bs] = ns;
      PS[((size_t)q*2 + 1)*M_ + bs] = nm;
      if (q == r + 1){ ps_next = ns; pm_next = nm; }
    }
    float bsum_s = 0.f, bsum_m = 0.f;
    for (int k = 0; k <= r; k++){ bsum_s += betas[k]; bsum_m += betas[8 + k]; }
    float xn = sr_s[(size_t)((r+1)*B_ + b)*S_ + t] + tok_s[bs] + ps_next + sb[0] + bsum_s;
    float yn = sr_m[(size_t)((r+1)*B_ + b)*S_ + t] + ent_m[bs] + pm_next + mb[0] + bsum_m;
    float* xn_buf = xlog + (size_t)((r+1) & 1) * (2*M_);
    xn_buf[bs] = xn;
    xn_buf[M_ + bs] = yn;
  }
}

extern "C" void kernel_launch(void* const* d_in, const int* in_sizes, int n_in,
                              void* d_out, int out_size, void* d_ws, size_t ws_size,
                              hipStream_t stream){
  (void)in_sizes; (void)n_in; (void)out_size; (void)ws_size;
  const int*   labels = (const int*)  d_in[0];
  const float* sr     = (const float*)d_in[1];
  const float* tok    = (const float*)d_in[2];
  const float* ent    = (const float*)d_in[3];
  const float* tmask  = (const float*)d_in[4];
  // d_in[5] entity_mask unused by reference
  const int*   spans  = (const int*)  d_in[6];
  const int*   c2t    = (const int*)  d_in[7];
  const int*   e2t    = (const int*)  d_in[8];
  const float* sw     = (const float*)d_in[9];
  const float* sb     = (const float*)d_in[10];
  const float* mw     = (const float*)d_in[11];
  const float* mb     = (const float*)d_in[12];
  const float* aw     = (const float*)d_in[13];
  const float* ab     = (const float*)d_in[14];
  float* out = (float*)d_out;
  char*  ws  = (char*)d_ws;

  size_t o = 0;
  auto take = [&](size_t bytes){ size_t c = o; o += (bytes + 255) & ~(size_t)255; return c; };
  float* sr_s  = (float*)(ws + take((size_t)R_*B_*S_*4));
  float* sr_m  = (float*)(ws + take((size_t)R_*B_*S_*4));
  float* tok_s = (float*)(ws + take((size_t)B_*S_*4));
  float* ent_m = (float*)(ws + take((size_t)B_*S_*4));
  float* a_s   = (float*)(ws + take((size_t)8*H_*4));
  float* a_m   = (float*)(ws + take((size_t)8*H_*4));
  float* V     = (float*)(ws + take((size_t)14*H_*4));
  float* betas = (float*)(ws + take(64));
  float* G     = (float*)(ws + take((size_t)14*M_*4));
  float* PS    = (float*)(ws + take((size_t)8*2*M_*4));   // zeroed in dots_all
  float* xlog  = (float*)(ws + take((size_t)2*2*M_*4));
  float* msum  = (float*)(ws + take(256));

  for (int k = 0; k < 7; k++)
    vec_chain_kernel<<<257, 256, 0, stream>>>(k, aw, ab, sw, mw, a_s, a_m, V, betas);
  dots_all_kernel<<<1024, 256, 0, stream>>>(sr, tok, ent, sw, mw, V, tmask,
                                            sr_s, sr_m, tok_s, ent_m, G, PS, msum, out);
  for (int r = 0; r < R_; r++){
    role_kernel<<<16, 512, 0, stream>>>(r, sr_s, sr_m, tok_s, ent_m, G, betas,
                                        sb, mb, c2t, e2t, spans, labels, msum, out,
                                        xlog, PS);
  }
}